// Round 18
// baseline (203.061 us; speedup 1.0000x reference)
//
#include <hip/hip_runtime.h>
#include <cfloat>
#include <cmath>

#define M     16384
#define K     4096
#define E     64
#define TOPK  8
#define GAP_THRESH 1e-4f

#define SPLIT 4                 // K-split (gate)
#define KPS   (K / SPLIT)       // 1024 k per wave
#define NCH   (KPS / 32)        // 32 chunks of k32

typedef __attribute__((ext_vector_type(8))) short bf16x8;
typedef __attribute__((ext_vector_type(4))) float f32x4;

// ws layout: [Whf 512KB][Wlf 512KB][part 16MB]

__device__ __forceinline__ short f2bf(float f) {           // RNE fp32->bf16
    unsigned u = __builtin_bit_cast(unsigned, f);
    u += 0x7FFFu + ((u >> 16) & 1u);
    return (short)(u >> 16);
}
__device__ __forceinline__ float bf2f(short h) {           // exact widen
    unsigned u = ((unsigned)(unsigned short)h) << 16;
    return __builtin_bit_cast(float, u);
}

// ---------------------------------------------------------------------------
// prep: Whf/Wlf in MFMA fragment order (proven r12-r17).
// ---------------------------------------------------------------------------
__global__ __launch_bounds__(256) void prep_kernel(const float* __restrict__ W,
                                                   short* __restrict__ Whf,
                                                   short* __restrict__ Wlf) {
    int t = blockIdx.x * 256 + threadIdx.x;   // t = e*4096 + k
    float w = W[t];
    short h = f2bf(w);
    short lo = f2bf(w - bf2f(h));
    int e = t >> 12, k = t & 4095;
    int gc = k >> 5, kk = k & 31;
    size_t fidx = (((size_t)gc * 4 + (e >> 4)) * 64 + (kk >> 3) * 16 + (e & 15)) * 8
                  + (kk & 7);
    Whf[fidx] = h;
    Wlf[fidx] = lo;
}

// ---------------------------------------------------------------------------
// MFMA gate (proven r12-r17, byte-identical): LDS-free, 2-deep register
// pipeline, fragment-ordered W, 16 waves/CU, no barriers.
// ---------------------------------------------------------------------------
struct XW {
    float4 xa, xb;
    bf16x8 h0, h1, h2, h3, l0, l1, l2, l3;
};

__device__ __forceinline__ void load_set(XW& s, const float* gx,
                                         const short* ph, const short* pl, int cc) {
    const int ko = cc * 32;
    s.xa = *reinterpret_cast<const float4*>(gx + ko);
    s.xb = *reinterpret_cast<const float4*>(gx + ko + 4);
    const short* bh = ph + (size_t)cc * 2048;
    const short* bl = pl + (size_t)cc * 2048;
    s.h0 = *reinterpret_cast<const bf16x8*>(bh);
    s.h1 = *reinterpret_cast<const bf16x8*>(bh + 512);
    s.h2 = *reinterpret_cast<const bf16x8*>(bh + 1024);
    s.h3 = *reinterpret_cast<const bf16x8*>(bh + 1536);
    s.l0 = *reinterpret_cast<const bf16x8*>(bl);
    s.l1 = *reinterpret_cast<const bf16x8*>(bl + 512);
    s.l2 = *reinterpret_cast<const bf16x8*>(bl + 1024);
    s.l3 = *reinterpret_cast<const bf16x8*>(bl + 1536);
}

__device__ __forceinline__ void compute_set(const XW& s, f32x4 acc[4]) {
    float vv[8] = {s.xa.x, s.xa.y, s.xa.z, s.xa.w, s.xb.x, s.xb.y, s.xb.z, s.xb.w};
    bf16x8 ah, al;
#pragma unroll
    for (int j = 0; j < 8; ++j) {
        short hh = f2bf(vv[j]);
        ah[j] = hh;
        al[j] = f2bf(vv[j] - bf2f(hh));
    }
    acc[0] = __builtin_amdgcn_mfma_f32_16x16x32_bf16(ah, s.h0, acc[0], 0, 0, 0);
    acc[0] = __builtin_amdgcn_mfma_f32_16x16x32_bf16(ah, s.l0, acc[0], 0, 0, 0);
    acc[0] = __builtin_amdgcn_mfma_f32_16x16x32_bf16(al, s.h0, acc[0], 0, 0, 0);
    acc[1] = __builtin_amdgcn_mfma_f32_16x16x32_bf16(ah, s.h1, acc[1], 0, 0, 0);
    acc[1] = __builtin_amdgcn_mfma_f32_16x16x32_bf16(ah, s.l1, acc[1], 0, 0, 0);
    acc[1] = __builtin_amdgcn_mfma_f32_16x16x32_bf16(al, s.h1, acc[1], 0, 0, 0);
    acc[2] = __builtin_amdgcn_mfma_f32_16x16x32_bf16(ah, s.h2, acc[2], 0, 0, 0);
    acc[2] = __builtin_amdgcn_mfma_f32_16x16x32_bf16(ah, s.l2, acc[2], 0, 0, 0);
    acc[2] = __builtin_amdgcn_mfma_f32_16x16x32_bf16(al, s.h2, acc[2], 0, 0, 0);
    acc[3] = __builtin_amdgcn_mfma_f32_16x16x32_bf16(ah, s.h3, acc[3], 0, 0, 0);
    acc[3] = __builtin_amdgcn_mfma_f32_16x16x32_bf16(ah, s.l3, acc[3], 0, 0, 0);
    acc[3] = __builtin_amdgcn_mfma_f32_16x16x32_bf16(al, s.h3, acc[3], 0, 0, 0);
}

__global__ __launch_bounds__(256) void gate_kernel(
    const float* __restrict__ x,
    const short* __restrict__ Whf,
    const short* __restrict__ Wlf,
    float* __restrict__ part)
{
    const int t  = threadIdx.x;
    const int l  = t & 63;
    const int wv = t >> 6;
    const int h    = blockIdx.x & (SPLIT - 1);        // 4 waves share k-slice
    const int row0 = (blockIdx.x >> 2) * 64 + wv * 16;
    const int k0   = h * KPS;

    const int kg   = l >> 4;                          // 0..3 k-granule
    const int xrow = row0 + (l & 15);

    const float* gx = x + (size_t)xrow * K + k0 + kg * 8;
    const short* ph = Whf + ((size_t)(k0 >> 5) * 4) * 512 + (size_t)l * 8;
    const short* pl = Wlf + ((size_t)(k0 >> 5) * 4) * 512 + (size_t)l * 8;

    f32x4 acc[4] = {{0,0,0,0},{0,0,0,0},{0,0,0,0},{0,0,0,0}};

    XW A, B;
    load_set(A, gx, ph, pl, 0);
    for (int c = 0; c < NCH; c += 2) {
        load_set(B, gx, ph, pl, c + 1);
        compute_set(A, acc);
        if (c + 2 < NCH) load_set(A, gx, ph, pl, c + 2);
        compute_set(B, acc);
    }

    // D layout (verified r10-r17): row = (l>>4)*4 + r, col = l&15
#pragma unroll
    for (int et = 0; et < 4; ++et)
#pragma unroll
        for (int r = 0; r < 4; ++r)
            part[((size_t)h * M + row0 + (l >> 4) * 4 + r) * E + et * 16 + (l & 15)]
                = acc[et][r];
}

// ---------------------------------------------------------------------------
// Reduce + top-9 + sparse softmax + INLINE block-local fp64 rescue (r18).
// Fuses the former fix_kernel: flagging is block-local, so the rescue is
// done cooperatively by the flagging block itself -- no list/count atomics,
// no 4th kernel dispatch, no cnt-dependent structure.  Unflagged blocks
// (~99%) pay only an LDS flag + 2 barriers.  Rescue per flagged row:
// stage x row in LDS (coalesced), wave w computes experts 16w..16w+15
// lane-parallel over k (16 independent 1KB W loads in flight per expert),
// fp64 butterfly reduce -> lsum, owner wave runs proven fp64 epilogue.
// ---------------------------------------------------------------------------
__global__ __launch_bounds__(256) void reduce_kernel(
    const float* __restrict__ part,
    const float* __restrict__ x,
    const float* __restrict__ W,
    const float* __restrict__ b,
    float* __restrict__ outp,
    float* __restrict__ outi)
{
    __shared__ float  xs[K];        // 16 KB
    __shared__ double lsum[E];      // 512 B
    __shared__ int    rflag[4];

    const int t = threadIdx.x;
    const int l = t & 63;
    const int w = t >> 6;
    const int row = blockIdx.x * 4 + w;

    float orig = b[l];
#pragma unroll
    for (int hh = 0; hh < SPLIT; ++hh)
        orig += part[((size_t)hh * M + row) * E + l];

    // fp32 top-9 ballot epilogue (proven r3-r17)
    float cur = orig;
    float vals[9];
    float myidxf = 0.0f;
    bool  sel = false;

#pragma unroll
    for (int i = 0; i < 9; ++i) {
        float m = cur;
#pragma unroll
        for (int off = 32; off > 0; off >>= 1)
            m = fmaxf(m, __shfl_xor(m, off, 64));
        unsigned long long msk = __ballot(cur == m);
        int il = __ffsll((long long)msk) - 1;
        vals[i] = m;
        if (l == il) { cur = -FLT_MAX; if (i < TOPK) sel = true; }
        if (i < TOPK && l == i) myidxf = (float)il;
    }

    float mingap = FLT_MAX;
#pragma unroll
    for (int i = 0; i < 8; ++i) mingap = fminf(mingap, vals[i] - vals[i + 1]);
    const bool flagged = (mingap < GAP_THRESH);          // wave-uniform

    if (!flagged) {
        float ssum = 0.0f;
#pragma unroll
        for (int i = 0; i < TOPK; ++i) ssum += expf(vals[i] - vals[0]);
        float p = sel ? (expf(orig - vals[0]) / ssum) : 0.0f;
        outp[(size_t)row * E + l] = p;
        if (l < TOPK) outi[(size_t)row * TOPK + l] = myidxf;
    }
    if (l == 0) rflag[w] = flagged ? 1 : 0;
    __syncthreads();

    // ---- block-local fp64 rescue for each flagged row ---------------------
#pragma unroll 1
    for (int r = 0; r < 4; ++r) {
        if (rflag[r] == 0) continue;                     // block-uniform
        const int rrow = blockIdx.x * 4 + r;

        // stage x row: 1024 float4 over 256 thr = 4 each, coalesced
        const float4* xr4 = reinterpret_cast<const float4*>(x + (size_t)rrow * K);
#pragma unroll
        for (int j = 0; j < 4; ++j)
            reinterpret_cast<float4*>(xs)[j * 256 + t] = xr4[j * 256 + t];
        __syncthreads();

        // wave w: experts 16w..16w+15, lane-parallel over k
#pragma unroll 2
        for (int ei = 0; ei < 16; ++ei) {
            const int e = w * 16 + ei;
            const float4* wr = reinterpret_cast<const float4*>(W + (size_t)e * K);
            double s = 0.0;
#pragma unroll
            for (int j = 0; j < 16; ++j) {
                float4 wv4 = wr[l + 64 * j];
                float4 xv  = reinterpret_cast<const float4*>(xs)[l + 64 * j];
                s = fma((double)xv.x, (double)wv4.x, s);
                s = fma((double)xv.y, (double)wv4.y, s);
                s = fma((double)xv.z, (double)wv4.z, s);
                s = fma((double)xv.w, (double)wv4.w, s);
            }
#pragma unroll
            for (int off = 32; off > 0; off >>= 1)
                s += __shfl_xor(s, off, 64);
            if (l == 0) lsum[e] = s;
        }
        __syncthreads();

        if (w == r) {   // owner wave: fp64 ballot epilogue (proven r2-r17)
            const double origd = lsum[l] + (double)b[l];
            double curd = origd;
            double dvals[TOPK];
            float  midx = 0.0f;
            bool   dsel = false;

#pragma unroll
            for (int tt = 0; tt < TOPK; ++tt) {
                double m = curd;
#pragma unroll
                for (int off = 32; off > 0; off >>= 1) {
                    double o = __shfl_xor(m, off, 64);
                    m = fmax(m, o);
                }
                unsigned long long msk = __ballot(curd == m);
                int il = __ffsll((long long)msk) - 1;
                dvals[tt] = m;
                if (l == il) { curd = -DBL_MAX; dsel = true; }
                if (l == tt)  midx = (float)il;
            }

            double ssum = 0.0;
#pragma unroll
            for (int tt = 0; tt < TOPK; ++tt) ssum += exp(dvals[tt] - dvals[0]);
            float p = dsel ? (float)(exp(origd - dvals[0]) / ssum) : 0.0f;

            outp[(size_t)rrow * E + l] = p;
            if (l < TOPK) outi[(size_t)rrow * TOPK + l] = midx;
        }
        __syncthreads();   // xs/lsum reused for next flagged row
    }
}

// ---------------------------------------------------------------------------
// Fallback (tiny ws): per-thread-row full fp64 from f32 W.  Correct, slow.
// ---------------------------------------------------------------------------
__global__ __launch_bounds__(64) void fallback_kernel(
    const float* __restrict__ x,
    const float* __restrict__ W,
    const float* __restrict__ b,
    float* __restrict__ outp,
    float* __restrict__ outi)
{
    const int row = blockIdx.x * 64 + threadIdx.x;
    double lg[64];
#pragma unroll
    for (int e = 0; e < 64; ++e) lg[e] = (double)b[e];
    const float* xr = x + (size_t)row * K;
    for (int k = 0; k < K; k += 4) {
        float4 xa = *reinterpret_cast<const float4*>(xr + k);
        double xd[4] = {(double)xa.x, (double)xa.y, (double)xa.z, (double)xa.w};
#pragma unroll
        for (int e = 0; e < 64; ++e) {
            const float* wp = W + (size_t)e * K + k;
            double a = lg[e];
#pragma unroll
            for (int j = 0; j < 4; ++j) a = fma(xd[j], (double)wp[j], a);
            lg[e] = a;
        }
    }
    unsigned long long selm = 0ull;
    double vals[TOPK]; int idx[TOPK];
#pragma unroll
    for (int i = 0; i < TOPK; ++i) {
        double m = -DBL_MAX; int mi = 0;
#pragma unroll
        for (int e = 0; e < 64; ++e) {
            bool gt = !((selm >> e) & 1ull) && (lg[e] > m);
            m = gt ? lg[e] : m; mi = gt ? e : mi;
        }
        vals[i] = m; idx[i] = mi; selm |= (1ull << mi);
    }
    double ssum = 0.0;
#pragma unroll
    for (int i = 0; i < TOPK; ++i) ssum += exp(vals[i] - vals[0]);
    double inv = 1.0 / ssum;
#pragma unroll
    for (int e = 0; e < 64; ++e)
        outp[(size_t)row * E + e] =
            ((selm >> e) & 1ull) ? (float)(exp(lg[e] - vals[0]) * inv) : 0.0f;
#pragma unroll
    for (int i = 0; i < TOPK; ++i)
        outi[(size_t)row * TOPK + i] = (float)idx[i];
}

// ---------------------------------------------------------------------------
extern "C" void kernel_launch(void* const* d_in, const int* in_sizes, int n_in,
                              void* d_out, int out_size, void* d_ws, size_t ws_size,
                              hipStream_t stream) {
    (void)in_sizes; (void)n_in; (void)out_size;
    const float* x = (const float*)d_in[0];
    const float* W = (const float*)d_in[1];
    const float* b = (const float*)d_in[2];

    float* outp = (float*)d_out;
    float* outi = outp + (size_t)M * E;

    const size_t wh_off   = 0;
    const size_t wl_off   = wh_off + sizeof(short) * (size_t)E * K;   // +512 KB
    const size_t part_off = wl_off + sizeof(short) * (size_t)E * K;   // +512 KB
    const size_t need     = part_off + (size_t)SPLIT * M * E * sizeof(float);

    if (ws_size >= need) {
        short*  Whf  = (short*)((char*)d_ws + wh_off);
        short*  Wlf  = (short*)((char*)d_ws + wl_off);
        float*  part = (float*)((char*)d_ws + part_off);

        prep_kernel<<<(E * K) / 256, 256, 0, stream>>>(W, Whf, Wlf);
        gate_kernel<<<(M / 64) * SPLIT, 256, 0, stream>>>(x, Whf, Wlf, part);
        reduce_kernel<<<M / 4, 256, 0, stream>>>(part, x, W, b, outp, outi);
    } else {
        fallback_kernel<<<M / 64, 64, 0, stream>>>(x, W, b, outp, outi);
    }
}

// Round 19
// 127.592 us; speedup vs baseline: 1.5915x; 1.5915x over previous
//
#include <hip/hip_runtime.h>
#include <cfloat>
#include <cmath>

#define M     16384
#define K     4096
#define E     64
#define TOPK  8
#define GAP_THRESH 1e-4f

#define SPLIT 4                 // K-split (gate)
#define KPS   (K / SPLIT)       // 1024 k per wave
#define NCH   (KPS / 32)        // 32 chunks of k32

typedef __attribute__((ext_vector_type(8))) short bf16x8;
typedef __attribute__((ext_vector_type(4))) float f32x4;

// ws layout: [Whf 512KB][Wlf 512KB][count 256B][list 64KB][part 16MB]

__device__ __forceinline__ short f2bf(float f) {           // RNE fp32->bf16
    unsigned u = __builtin_bit_cast(unsigned, f);
    u += 0x7FFFu + ((u >> 16) & 1u);
    return (short)(u >> 16);
}
__device__ __forceinline__ float bf2f(short h) {           // exact widen
    unsigned u = ((unsigned)(unsigned short)h) << 16;
    return __builtin_bit_cast(float, u);
}

// ---------------------------------------------------------------------------
// prep (r17 byte-identical): Whf/Wlf in MFMA fragment order; zero counter.
// ---------------------------------------------------------------------------
__global__ __launch_bounds__(256) void prep_kernel(const float* __restrict__ W,
                                                   short* __restrict__ Whf,
                                                   short* __restrict__ Wlf,
                                                   int* __restrict__ count) {
    int t = blockIdx.x * 256 + threadIdx.x;   // t = e*4096 + k
    float w = W[t];
    short h = f2bf(w);
    short lo = f2bf(w - bf2f(h));
    int e = t >> 12, k = t & 4095;
    int gc = k >> 5, kk = k & 31;
    size_t fidx = (((size_t)gc * 4 + (e >> 4)) * 64 + (kk >> 3) * 16 + (e & 15)) * 8
                  + (kk & 7);
    Whf[fidx] = h;
    Wlf[fidx] = lo;
    if (t == 0) *count = 0;
}

// ---------------------------------------------------------------------------
// MFMA gate (r12-r17 byte-identical): LDS-free, 2-deep register pipeline,
// fragment-ordered W, 16 waves/CU, no barriers.
// ---------------------------------------------------------------------------
struct XW {
    float4 xa, xb;
    bf16x8 h0, h1, h2, h3, l0, l1, l2, l3;
};

__device__ __forceinline__ void load_set(XW& s, const float* gx,
                                         const short* ph, const short* pl, int cc) {
    const int ko = cc * 32;
    s.xa = *reinterpret_cast<const float4*>(gx + ko);
    s.xb = *reinterpret_cast<const float4*>(gx + ko + 4);
    const short* bh = ph + (size_t)cc * 2048;
    const short* bl = pl + (size_t)cc * 2048;
    s.h0 = *reinterpret_cast<const bf16x8*>(bh);
    s.h1 = *reinterpret_cast<const bf16x8*>(bh + 512);
    s.h2 = *reinterpret_cast<const bf16x8*>(bh + 1024);
    s.h3 = *reinterpret_cast<const bf16x8*>(bh + 1536);
    s.l0 = *reinterpret_cast<const bf16x8*>(bl);
    s.l1 = *reinterpret_cast<const bf16x8*>(bl + 512);
    s.l2 = *reinterpret_cast<const bf16x8*>(bl + 1024);
    s.l3 = *reinterpret_cast<const bf16x8*>(bl + 1536);
}

__device__ __forceinline__ void compute_set(const XW& s, f32x4 acc[4]) {
    float vv[8] = {s.xa.x, s.xa.y, s.xa.z, s.xa.w, s.xb.x, s.xb.y, s.xb.z, s.xb.w};
    bf16x8 ah, al;
#pragma unroll
    for (int j = 0; j < 8; ++j) {
        short hh = f2bf(vv[j]);
        ah[j] = hh;
        al[j] = f2bf(vv[j] - bf2f(hh));
    }
    acc[0] = __builtin_amdgcn_mfma_f32_16x16x32_bf16(ah, s.h0, acc[0], 0, 0, 0);
    acc[0] = __builtin_amdgcn_mfma_f32_16x16x32_bf16(ah, s.l0, acc[0], 0, 0, 0);
    acc[0] = __builtin_amdgcn_mfma_f32_16x16x32_bf16(al, s.h0, acc[0], 0, 0, 0);
    acc[1] = __builtin_amdgcn_mfma_f32_16x16x32_bf16(ah, s.h1, acc[1], 0, 0, 0);
    acc[1] = __builtin_amdgcn_mfma_f32_16x16x32_bf16(ah, s.l1, acc[1], 0, 0, 0);
    acc[1] = __builtin_amdgcn_mfma_f32_16x16x32_bf16(al, s.h1, acc[1], 0, 0, 0);
    acc[2] = __builtin_amdgcn_mfma_f32_16x16x32_bf16(ah, s.h2, acc[2], 0, 0, 0);
    acc[2] = __builtin_amdgcn_mfma_f32_16x16x32_bf16(ah, s.l2, acc[2], 0, 0, 0);
    acc[2] = __builtin_amdgcn_mfma_f32_16x16x32_bf16(al, s.h2, acc[2], 0, 0, 0);
    acc[3] = __builtin_amdgcn_mfma_f32_16x16x32_bf16(ah, s.h3, acc[3], 0, 0, 0);
    acc[3] = __builtin_amdgcn_mfma_f32_16x16x32_bf16(ah, s.l3, acc[3], 0, 0, 0);
    acc[3] = __builtin_amdgcn_mfma_f32_16x16x32_bf16(al, s.h3, acc[3], 0, 0, 0);
}

__global__ __launch_bounds__(256) void gate_kernel(
    const float* __restrict__ x,
    const short* __restrict__ Whf,
    const short* __restrict__ Wlf,
    float* __restrict__ part)
{
    const int t  = threadIdx.x;
    const int l  = t & 63;
    const int wv = t >> 6;
    const int h    = blockIdx.x & (SPLIT - 1);        // 4 waves share k-slice
    const int row0 = (blockIdx.x >> 2) * 64 + wv * 16;
    const int k0   = h * KPS;

    const int kg   = l >> 4;                          // 0..3 k-granule
    const int xrow = row0 + (l & 15);

    const float* gx = x + (size_t)xrow * K + k0 + kg * 8;
    const short* ph = Whf + ((size_t)(k0 >> 5) * 4) * 512 + (size_t)l * 8;
    const short* pl = Wlf + ((size_t)(k0 >> 5) * 4) * 512 + (size_t)l * 8;

    f32x4 acc[4] = {{0,0,0,0},{0,0,0,0},{0,0,0,0},{0,0,0,0}};

    XW A, B;
    load_set(A, gx, ph, pl, 0);
    for (int c = 0; c < NCH; c += 2) {
        load_set(B, gx, ph, pl, c + 1);
        compute_set(A, acc);
        if (c + 2 < NCH) load_set(A, gx, ph, pl, c + 2);
        compute_set(B, acc);
    }

    // D layout (verified r10-r18): row = (l>>4)*4 + r, col = l&15
#pragma unroll
    for (int et = 0; et < 4; ++et)
#pragma unroll
        for (int r = 0; r < 4; ++r)
            part[((size_t)h * M + row0 + (l >> 4) * 4 + r) * E + et * 16 + (l & 15)]
                = acc[et][r];
}

// ---------------------------------------------------------------------------
// Reduce + top-9 + sparse softmax + ambiguity flag (r17 byte-identical).
// ---------------------------------------------------------------------------
__global__ __launch_bounds__(256) void reduce_kernel(
    const float* __restrict__ part,
    const float* __restrict__ b,
    float* __restrict__ outp,
    float* __restrict__ outi,
    int*   __restrict__ count,
    int*   __restrict__ list)
{
    const int lane = threadIdx.x & 63;
    const int w    = threadIdx.x >> 6;
    const int row  = blockIdx.x * 4 + w;

    float orig = b[lane];
#pragma unroll
    for (int hh = 0; hh < SPLIT; ++hh)
        orig += part[((size_t)hh * M + row) * E + lane];

    float cur = orig;
    float vals[9];
    float myidxf = 0.0f;
    bool  sel = false;

#pragma unroll
    for (int i = 0; i < 9; ++i) {
        float m = cur;
#pragma unroll
        for (int off = 32; off > 0; off >>= 1)
            m = fmaxf(m, __shfl_xor(m, off, 64));
        unsigned long long msk = __ballot(cur == m);
        int il = __ffsll((long long)msk) - 1;
        vals[i] = m;
        if (lane == il) { cur = -FLT_MAX; if (i < TOPK) sel = true; }
        if (i < TOPK && lane == i) myidxf = (float)il;
    }

    float ssum = 0.0f;
#pragma unroll
    for (int i = 0; i < TOPK; ++i) ssum += expf(vals[i] - vals[0]);
    float p = sel ? (expf(orig - vals[0]) / ssum) : 0.0f;

    outp[(size_t)row * E + lane] = p;
    if (lane < TOPK) outi[(size_t)row * TOPK + lane] = myidxf;

    float mingap = FLT_MAX;
#pragma unroll
    for (int i = 0; i < 8; ++i) mingap = fminf(mingap, vals[i] - vals[i + 1]);
    if (lane == 0 && mingap < GAP_THRESH) {
        int pos = atomicAdd(count, 1);
        if (pos < M) list[pos] = row;
    }
}

// ---------------------------------------------------------------------------
// fp64 rescue, r19: r12-recipe pipeline.  r13-r18 rescues all serialized
// their W loads (partial-unroll loops blew the VGPR budget -> dependent
// ~300cyc chains; r17 fix ~75us by subtraction).  Now: one row per 256-thr
// block; wave wv owns experts 16wv..16wv+15 FULL-K in 2 groups of 8
// streams; named 2-deep wa/wb double-buffer with '#pragma unroll 1' j-loop
// (small code, static element indices, ~110 VGPR); W bases wave-uniform
// (SGPR) + lane voffset.  fp64 butterfly -> lsum -> wave 0 runs the proven
// fp64 ballot epilogue.  ~6us per flagged block, all blocks parallel.
// ---------------------------------------------------------------------------
__global__ __launch_bounds__(256) void fix_kernel(
    const float* __restrict__ x,
    const float* __restrict__ W,
    const float* __restrict__ b,
    float* __restrict__ outp,
    float* __restrict__ outi,
    const int* __restrict__ count,
    const int* __restrict__ list)
{
    __shared__ float  xs[K];         // 16 KB
    __shared__ double lsum[E];       // 512 B
    const int t   = threadIdx.x;
    const int l   = t & 63;
    const int wv  = t >> 6;          // 0..3
    const int cnt = *count;

    for (int i = blockIdx.x; i < cnt; i += gridDim.x) {
        const int row = list[i];

        // stage x row: 1024 float4 over 256 thr = 4 each, coalesced
        const float4* xr4 = reinterpret_cast<const float4*>(x + (size_t)row * K);
#pragma unroll
        for (int j = 0; j < 4; ++j)
            reinterpret_cast<float4*>(xs)[j * 256 + t] = xr4[j * 256 + t];
        __syncthreads();

#pragma unroll 1
        for (int g = 0; g < 2; ++g) {
            const int e0 = wv * 16 + g * 8;
            const float4* wp[8];
#pragma unroll
            for (int e8 = 0; e8 < 8; ++e8)
                wp[e8] = reinterpret_cast<const float4*>(W + (size_t)(e0 + e8) * K);

            double s[8] = {};
            float4 wa[8], wb[8];
#pragma unroll
            for (int e8 = 0; e8 < 8; ++e8) wa[e8] = wp[e8][l];       // j=0

#pragma unroll 1
            for (int j = 0; j < 16; j += 2) {
#pragma unroll
                for (int e8 = 0; e8 < 8; ++e8)                        // j+1
                    wb[e8] = wp[e8][l + 64 * (j + 1)];
                float4 xv = reinterpret_cast<const float4*>(xs)[l + 64 * j];
#pragma unroll
                for (int e8 = 0; e8 < 8; ++e8) {
                    s[e8] = fma((double)xv.x, (double)wa[e8].x, s[e8]);
                    s[e8] = fma((double)xv.y, (double)wa[e8].y, s[e8]);
                    s[e8] = fma((double)xv.z, (double)wa[e8].z, s[e8]);
                    s[e8] = fma((double)xv.w, (double)wa[e8].w, s[e8]);
                }
                if (j + 2 < 16) {
#pragma unroll
                    for (int e8 = 0; e8 < 8; ++e8)                    // j+2
                        wa[e8] = wp[e8][l + 64 * (j + 2)];
                }
                xv = reinterpret_cast<const float4*>(xs)[l + 64 * (j + 1)];
#pragma unroll
                for (int e8 = 0; e8 < 8; ++e8) {
                    s[e8] = fma((double)xv.x, (double)wb[e8].x, s[e8]);
                    s[e8] = fma((double)xv.y, (double)wb[e8].y, s[e8]);
                    s[e8] = fma((double)xv.z, (double)wb[e8].z, s[e8]);
                    s[e8] = fma((double)xv.w, (double)wb[e8].w, s[e8]);
                }
            }

            // fp64 butterfly reduce per expert
#pragma unroll
            for (int e8 = 0; e8 < 8; ++e8) {
                double v = s[e8];
#pragma unroll
                for (int off = 32; off > 0; off >>= 1)
                    v += __shfl_xor(v, off, 64);
                if (l == 0) lsum[e0 + e8] = v;
            }
        }
        __syncthreads();

        if (wv == 0) {    // proven fp64 ballot epilogue (r2-r18)
            const double orig = lsum[l] + (double)b[l];
            double cur = orig;

            double vals[TOPK];
            float  myidxf = 0.0f;
            bool   sel = false;

#pragma unroll
            for (int tt = 0; tt < TOPK; ++tt) {
                double m = cur;
#pragma unroll
                for (int off = 32; off > 0; off >>= 1) {
                    double o = __shfl_xor(m, off, 64);
                    m = fmax(m, o);
                }
                unsigned long long msk = __ballot(cur == m);
                int il = __ffsll((long long)msk) - 1;
                vals[tt] = m;
                if (l == il) { cur = -DBL_MAX; sel = true; }
                if (l == tt)  myidxf = (float)il;
            }

            double ssum = 0.0;
#pragma unroll
            for (int tt = 0; tt < TOPK; ++tt) ssum += exp(vals[tt] - vals[0]);
            float p = sel ? (float)(exp(orig - vals[0]) / ssum) : 0.0f;

            outp[(size_t)row * E + l] = p;
            if (l < TOPK) outi[(size_t)row * TOPK + l] = myidxf;
        }
        __syncthreads();   // xs/lsum reused next pass
    }
}

// ---------------------------------------------------------------------------
// Fallback (tiny ws): per-thread-row full fp64 from f32 W.  Correct, slow.
// ---------------------------------------------------------------------------
__global__ __launch_bounds__(64) void fallback_kernel(
    const float* __restrict__ x,
    const float* __restrict__ W,
    const float* __restrict__ b,
    float* __restrict__ outp,
    float* __restrict__ outi)
{
    const int row = blockIdx.x * 64 + threadIdx.x;
    double lg[64];
#pragma unroll
    for (int e = 0; e < 64; ++e) lg[e] = (double)b[e];
    const float* xr = x + (size_t)row * K;
    for (int k = 0; k < K; k += 4) {
        float4 xa = *reinterpret_cast<const float4*>(xr + k);
        double xd[4] = {(double)xa.x, (double)xa.y, (double)xa.z, (double)xa.w};
#pragma unroll
        for (int e = 0; e < 64; ++e) {
            const float* wp = W + (size_t)e * K + k;
            double a = lg[e];
#pragma unroll
            for (int j = 0; j < 4; ++j) a = fma(xd[j], (double)wp[j], a);
            lg[e] = a;
        }
    }
    unsigned long long selm = 0ull;
    double vals[TOPK]; int idx[TOPK];
#pragma unroll
    for (int i = 0; i < TOPK; ++i) {
        double m = -DBL_MAX; int mi = 0;
#pragma unroll
        for (int e = 0; e < 64; ++e) {
            bool gt = !((selm >> e) & 1ull) && (lg[e] > m);
            m = gt ? lg[e] : m; mi = gt ? e : mi;
        }
        vals[i] = m; idx[i] = mi; selm |= (1ull << mi);
    }
    double ssum = 0.0;
#pragma unroll
    for (int i = 0; i < TOPK; ++i) ssum += exp(vals[i] - vals[0]);
    double inv = 1.0 / ssum;
#pragma unroll
    for (int e = 0; e < 64; ++e)
        outp[(size_t)row * E + e] =
            ((selm >> e) & 1ull) ? (float)(exp(lg[e] - vals[0]) * inv) : 0.0f;
#pragma unroll
    for (int i = 0; i < TOPK; ++i)
        outi[(size_t)row * TOPK + i] = (float)idx[i];
}

// ---------------------------------------------------------------------------
extern "C" void kernel_launch(void* const* d_in, const int* in_sizes, int n_in,
                              void* d_out, int out_size, void* d_ws, size_t ws_size,
                              hipStream_t stream) {
    (void)in_sizes; (void)n_in; (void)out_size;
    const float* x = (const float*)d_in[0];
    const float* W = (const float*)d_in[1];
    const float* b = (const float*)d_in[2];

    float* outp = (float*)d_out;
    float* outi = outp + (size_t)M * E;

    const size_t wh_off   = 0;
    const size_t wl_off   = wh_off + sizeof(short) * (size_t)E * K;   // +512 KB
    const size_t cnt_off  = wl_off + sizeof(short) * (size_t)E * K;   // +512 KB
    const size_t list_off = cnt_off + 256;
    const size_t part_off = list_off + (size_t)M * sizeof(int);
    const size_t need     = part_off + (size_t)SPLIT * M * E * sizeof(float);

    if (ws_size >= need) {
        short*  Whf  = (short*)((char*)d_ws + wh_off);
        short*  Wlf  = (short*)((char*)d_ws + wl_off);
        int*    cnt  = (int*)((char*)d_ws + cnt_off);
        int*    list = (int*)((char*)d_ws + list_off);
        float*  part = (float*)((char*)d_ws + part_off);

        prep_kernel<<<(E * K) / 256, 256, 0, stream>>>(W, Whf, Wlf, cnt);
        gate_kernel<<<(M / 64) * SPLIT, 256, 0, stream>>>(x, Whf, Wlf, part);
        reduce_kernel<<<M / 4, 256, 0, stream>>>(part, b, outp, outi, cnt, list);
        fix_kernel<<<1024, 256, 0, stream>>>(x, W, b, outp, outi, cnt, list);
    } else {
        fallback_kernel<<<M / 64, 64, 0, stream>>>(x, W, b, outp, outi);
    }
}

// Round 20
// 127.341 us; speedup vs baseline: 1.5946x; 1.0020x over previous
//
#include <hip/hip_runtime.h>
#include <cfloat>
#include <cmath>

#define M     16384
#define K     4096
#define E     64
#define TOPK  8
#define GAP_THRESH 1e-4f

#define SPLIT 4                 // K-split (gate)
#define KPS   (K / SPLIT)       // 1024 k per wave
#define NCH   (KPS / 32)        // 32 chunks of k32
#define RCAP  2048              // max rescued rows (10x expected ~150)
#define FKS   8                 // rescue K-split

typedef __attribute__((ext_vector_type(8))) short bf16x8;
typedef __attribute__((ext_vector_type(4))) float f32x4;

// ws layout: [Whf 512K][Wlf 512K][count 256B][list 64KB][part 16MB][dsum 8MB]

__device__ __forceinline__ short f2bf(float f) {           // RNE fp32->bf16
    unsigned u = __builtin_bit_cast(unsigned, f);
    u += 0x7FFFu + ((u >> 16) & 1u);
    return (short)(u >> 16);
}
__device__ __forceinline__ float bf2f(short h) {           // exact widen
    unsigned u = ((unsigned)(unsigned short)h) << 16;
    return __builtin_bit_cast(float, u);
}

// ---------------------------------------------------------------------------
// prep (r17-r19 byte-identical): Whf/Wlf in MFMA fragment order; zero count.
// ---------------------------------------------------------------------------
__global__ __launch_bounds__(256) void prep_kernel(const float* __restrict__ W,
                                                   short* __restrict__ Whf,
                                                   short* __restrict__ Wlf,
                                                   int* __restrict__ count) {
    int t = blockIdx.x * 256 + threadIdx.x;   // t = e*4096 + k
    float w = W[t];
    short h = f2bf(w);
    short lo = f2bf(w - bf2f(h));
    int e = t >> 12, k = t & 4095;
    int gc = k >> 5, kk = k & 31;
    size_t fidx = (((size_t)gc * 4 + (e >> 4)) * 64 + (kk >> 3) * 16 + (e & 15)) * 8
                  + (kk & 7);
    Whf[fidx] = h;
    Wlf[fidx] = lo;
    if (t == 0) *count = 0;
}

// ---------------------------------------------------------------------------
// MFMA gate (r12-r19 byte-identical): LDS-free, 2-deep register pipeline,
// fragment-ordered W, 16 waves/CU, no barriers.
// ---------------------------------------------------------------------------
struct XW {
    float4 xa, xb;
    bf16x8 h0, h1, h2, h3, l0, l1, l2, l3;
};

__device__ __forceinline__ void load_set(XW& s, const float* gx,
                                         const short* ph, const short* pl, int cc) {
    const int ko = cc * 32;
    s.xa = *reinterpret_cast<const float4*>(gx + ko);
    s.xb = *reinterpret_cast<const float4*>(gx + ko + 4);
    const short* bh = ph + (size_t)cc * 2048;
    const short* bl = pl + (size_t)cc * 2048;
    s.h0 = *reinterpret_cast<const bf16x8*>(bh);
    s.h1 = *reinterpret_cast<const bf16x8*>(bh + 512);
    s.h2 = *reinterpret_cast<const bf16x8*>(bh + 1024);
    s.h3 = *reinterpret_cast<const bf16x8*>(bh + 1536);
    s.l0 = *reinterpret_cast<const bf16x8*>(bl);
    s.l1 = *reinterpret_cast<const bf16x8*>(bl + 512);
    s.l2 = *reinterpret_cast<const bf16x8*>(bl + 1024);
    s.l3 = *reinterpret_cast<const bf16x8*>(bl + 1536);
}

__device__ __forceinline__ void compute_set(const XW& s, f32x4 acc[4]) {
    float vv[8] = {s.xa.x, s.xa.y, s.xa.z, s.xa.w, s.xb.x, s.xb.y, s.xb.z, s.xb.w};
    bf16x8 ah, al;
#pragma unroll
    for (int j = 0; j < 8; ++j) {
        short hh = f2bf(vv[j]);
        ah[j] = hh;
        al[j] = f2bf(vv[j] - bf2f(hh));
    }
    acc[0] = __builtin_amdgcn_mfma_f32_16x16x32_bf16(ah, s.h0, acc[0], 0, 0, 0);
    acc[0] = __builtin_amdgcn_mfma_f32_16x16x32_bf16(ah, s.l0, acc[0], 0, 0, 0);
    acc[0] = __builtin_amdgcn_mfma_f32_16x16x32_bf16(al, s.h0, acc[0], 0, 0, 0);
    acc[1] = __builtin_amdgcn_mfma_f32_16x16x32_bf16(ah, s.h1, acc[1], 0, 0, 0);
    acc[1] = __builtin_amdgcn_mfma_f32_16x16x32_bf16(ah, s.l1, acc[1], 0, 0, 0);
    acc[1] = __builtin_amdgcn_mfma_f32_16x16x32_bf16(al, s.h1, acc[1], 0, 0, 0);
    acc[2] = __builtin_amdgcn_mfma_f32_16x16x32_bf16(ah, s.h2, acc[2], 0, 0, 0);
    acc[2] = __builtin_amdgcn_mfma_f32_16x16x32_bf16(ah, s.l2, acc[2], 0, 0, 0);
    acc[2] = __builtin_amdgcn_mfma_f32_16x16x32_bf16(al, s.h2, acc[2], 0, 0, 0);
    acc[3] = __builtin_amdgcn_mfma_f32_16x16x32_bf16(ah, s.h3, acc[3], 0, 0, 0);
    acc[3] = __builtin_amdgcn_mfma_f32_16x16x32_bf16(ah, s.l3, acc[3], 0, 0, 0);
    acc[3] = __builtin_amdgcn_mfma_f32_16x16x32_bf16(al, s.h3, acc[3], 0, 0, 0);
}

__global__ __launch_bounds__(256) void gate_kernel(
    const float* __restrict__ x,
    const short* __restrict__ Whf,
    const short* __restrict__ Wlf,
    float* __restrict__ part)
{
    const int t  = threadIdx.x;
    const int l  = t & 63;
    const int wv = t >> 6;
    const int h    = blockIdx.x & (SPLIT - 1);        // 4 waves share k-slice
    const int row0 = (blockIdx.x >> 2) * 64 + wv * 16;
    const int k0   = h * KPS;

    const int kg   = l >> 4;                          // 0..3 k-granule
    const int xrow = row0 + (l & 15);

    const float* gx = x + (size_t)xrow * K + k0 + kg * 8;
    const short* ph = Whf + ((size_t)(k0 >> 5) * 4) * 512 + (size_t)l * 8;
    const short* pl = Wlf + ((size_t)(k0 >> 5) * 4) * 512 + (size_t)l * 8;

    f32x4 acc[4] = {{0,0,0,0},{0,0,0,0},{0,0,0,0},{0,0,0,0}};

    XW A, B;
    load_set(A, gx, ph, pl, 0);
    for (int c = 0; c < NCH; c += 2) {
        load_set(B, gx, ph, pl, c + 1);
        compute_set(A, acc);
        if (c + 2 < NCH) load_set(A, gx, ph, pl, c + 2);
        compute_set(B, acc);
    }

    // D layout (verified r10-r19): row = (l>>4)*4 + r, col = l&15
#pragma unroll
    for (int et = 0; et < 4; ++et)
#pragma unroll
        for (int r = 0; r < 4; ++r)
            part[((size_t)h * M + row0 + (l >> 4) * 4 + r) * E + et * 16 + (l & 15)]
                = acc[et][r];
}

// ---------------------------------------------------------------------------
// Reduce + top-9 + sparse softmax + ambiguity flag (r17-r19 byte-identical).
// ---------------------------------------------------------------------------
__global__ __launch_bounds__(256) void reduce_kernel(
    const float* __restrict__ part,
    const float* __restrict__ b,
    float* __restrict__ outp,
    float* __restrict__ outi,
    int*   __restrict__ count,
    int*   __restrict__ list)
{
    const int lane = threadIdx.x & 63;
    const int w    = threadIdx.x >> 6;
    const int row  = blockIdx.x * 4 + w;

    float orig = b[lane];
#pragma unroll
    for (int hh = 0; hh < SPLIT; ++hh)
        orig += part[((size_t)hh * M + row) * E + lane];

    float cur = orig;
    float vals[9];
    float myidxf = 0.0f;
    bool  sel = false;

#pragma unroll
    for (int i = 0; i < 9; ++i) {
        float m = cur;
#pragma unroll
        for (int off = 32; off > 0; off >>= 1)
            m = fmaxf(m, __shfl_xor(m, off, 64));
        unsigned long long msk = __ballot(cur == m);
        int il = __ffsll((long long)msk) - 1;
        vals[i] = m;
        if (lane == il) { cur = -FLT_MAX; if (i < TOPK) sel = true; }
        if (i < TOPK && lane == i) myidxf = (float)il;
    }

    float ssum = 0.0f;
#pragma unroll
    for (int i = 0; i < TOPK; ++i) ssum += expf(vals[i] - vals[0]);
    float p = sel ? (expf(orig - vals[0]) / ssum) : 0.0f;

    outp[(size_t)row * E + lane] = p;
    if (lane < TOPK) outi[(size_t)row * TOPK + lane] = myidxf;

    float mingap = FLT_MAX;
#pragma unroll
    for (int i = 0; i < 8; ++i) mingap = fminf(mingap, vals[i] - vals[i + 1]);
    if (lane == 0 && mingap < GAP_THRESH) {
        int pos = atomicAdd(count, 1);
        if (pos < M) list[pos] = row;
    }
}

// ---------------------------------------------------------------------------
// fix1 (r20): fp64 partial dots, K-SPLIT 8 across blocks.  Empirical law from
// r12-r19: a rescue wave streams W at only ~3.4 GB/s (one load in flight)
// regardless of structure -> rescue time ~ per-wave W bytes.  So cut bytes:
// block = one (row, ks) pair, wave owns 16 experts x 512 k = 32 KB of W in
// 16 fully-unrolled independent streams (2 j-steps).  Butterfly-reduce ->
// dsum[row][ks][e].  ~1600 active blocks, all parallel.
// ---------------------------------------------------------------------------
__global__ __launch_bounds__(256) void fix1_kernel(
    const float* __restrict__ x,
    const float* __restrict__ W,
    double* __restrict__ dsum,          // [RCAP][FKS][E]
    const int* __restrict__ count,
    const int* __restrict__ list)
{
    __shared__ float xsl[512];          // 2 KB: this block's k-slice
    const int t   = threadIdx.x;
    const int l   = t & 63;
    const int wv  = t >> 6;             // 0..3
    const int tot = min(*count, RCAP) * FKS;

    for (int p = blockIdx.x; p < tot; p += gridDim.x) {
        const int i   = p >> 3;         // rescue index
        const int ks  = p & 7;          // k-slice 0..7
        const int row = list[i];
        const int k0  = ks << 9;        // ks * 512

        // stage the 512-float slice: 128 float4 by threads 0..127
        if (t < 128)
            reinterpret_cast<float4*>(xsl)[t] =
                reinterpret_cast<const float4*>(x + (size_t)row * K + k0)[t];
        __syncthreads();

        const float4* xs4 = reinterpret_cast<const float4*>(xsl);

#pragma unroll
        for (int g = 0; g < 2; ++g) {
            const int e0 = wv * 16 + g * 8;
            // 16 independent W loads (8 streams x 2 j-steps), all issued up front
            float4 w0[8], w1[8];
#pragma unroll
            for (int e8 = 0; e8 < 8; ++e8) {
                const float4* wp = reinterpret_cast<const float4*>(
                    W + (size_t)(e0 + e8) * K + k0);
                w0[e8] = wp[l];
                w1[e8] = wp[l + 64];
            }
            float4 xv0 = xs4[l];
            float4 xv1 = xs4[l + 64];

            double s[8];
#pragma unroll
            for (int e8 = 0; e8 < 8; ++e8) {
                double a = 0.0;
                a = fma((double)xv0.x, (double)w0[e8].x, a);
                a = fma((double)xv0.y, (double)w0[e8].y, a);
                a = fma((double)xv0.z, (double)w0[e8].z, a);
                a = fma((double)xv0.w, (double)w0[e8].w, a);
                a = fma((double)xv1.x, (double)w1[e8].x, a);
                a = fma((double)xv1.y, (double)w1[e8].y, a);
                a = fma((double)xv1.z, (double)w1[e8].z, a);
                a = fma((double)xv1.w, (double)w1[e8].w, a);
                s[e8] = a;
            }

            // fp64 butterfly per expert; lane 0 writes the partial
#pragma unroll
            for (int e8 = 0; e8 < 8; ++e8) {
                double v = s[e8];
#pragma unroll
                for (int off = 32; off > 0; off >>= 1)
                    v += __shfl_xor(v, off, 64);
                if (l == 0)
                    dsum[((size_t)i * FKS + ks) * E + e0 + e8] = v;
            }
        }
        __syncthreads();   // xsl reused next pass
    }
}

// ---------------------------------------------------------------------------
// fix2 (r20): combine the 8 fp64 partials per rescued row + proven fp64
// ballot top-8/softmax epilogue.  One wave per row; 4 KB of reads per block.
// ---------------------------------------------------------------------------
__global__ __launch_bounds__(64) void fix2_kernel(
    const double* __restrict__ dsum,
    const float*  __restrict__ b,
    float* __restrict__ outp,
    float* __restrict__ outi,
    const int* __restrict__ count,
    const int* __restrict__ list)
{
    const int l   = threadIdx.x;
    const int cnt = min(*count, RCAP);

    for (int i = blockIdx.x; i < cnt; i += gridDim.x) {
        const int row = list[i];

        double orig = (double)b[l];
#pragma unroll
        for (int ks = 0; ks < FKS; ++ks)
            orig += dsum[((size_t)i * FKS + ks) * E + l];

        double cur = orig;
        double vals[TOPK];
        float  myidxf = 0.0f;
        bool   sel = false;

#pragma unroll
        for (int tt = 0; tt < TOPK; ++tt) {
            double m = cur;
#pragma unroll
            for (int off = 32; off > 0; off >>= 1) {
                double o = __shfl_xor(m, off, 64);
                m = fmax(m, o);
            }
            unsigned long long msk = __ballot(cur == m);
            int il = __ffsll((long long)msk) - 1;
            vals[tt] = m;
            if (l == il) { cur = -DBL_MAX; sel = true; }
            if (l == tt)  myidxf = (float)il;
        }

        double ssum = 0.0;
#pragma unroll
        for (int tt = 0; tt < TOPK; ++tt) ssum += exp(vals[tt] - vals[0]);
        float p = sel ? (float)(exp(orig - vals[0]) / ssum) : 0.0f;

        outp[(size_t)row * E + l] = p;
        if (l < TOPK) outi[(size_t)row * TOPK + l] = myidxf;
    }
}

// ---------------------------------------------------------------------------
// Fallback (tiny ws): per-thread-row full fp64 from f32 W.  Correct, slow.
// ---------------------------------------------------------------------------
__global__ __launch_bounds__(64) void fallback_kernel(
    const float* __restrict__ x,
    const float* __restrict__ W,
    const float* __restrict__ b,
    float* __restrict__ outp,
    float* __restrict__ outi)
{
    const int row = blockIdx.x * 64 + threadIdx.x;
    double lg[64];
#pragma unroll
    for (int e = 0; e < 64; ++e) lg[e] = (double)b[e];
    const float* xr = x + (size_t)row * K;
    for (int k = 0; k < K; k += 4) {
        float4 xa = *reinterpret_cast<const float4*>(xr + k);
        double xd[4] = {(double)xa.x, (double)xa.y, (double)xa.z, (double)xa.w};
#pragma unroll
        for (int e = 0; e < 64; ++e) {
            const float* wp = W + (size_t)e * K + k;
            double a = lg[e];
#pragma unroll
            for (int j = 0; j < 4; ++j) a = fma(xd[j], (double)wp[j], a);
            lg[e] = a;
        }
    }
    unsigned long long selm = 0ull;
    double vals[TOPK]; int idx[TOPK];
#pragma unroll
    for (int i = 0; i < TOPK; ++i) {
        double m = -DBL_MAX; int mi = 0;
#pragma unroll
        for (int e = 0; e < 64; ++e) {
            bool gt = !((selm >> e) & 1ull) && (lg[e] > m);
            m = gt ? lg[e] : m; mi = gt ? e : mi;
        }
        vals[i] = m; idx[i] = mi; selm |= (1ull << mi);
    }
    double ssum = 0.0;
#pragma unroll
    for (int i = 0; i < TOPK; ++i) ssum += exp(vals[i] - vals[0]);
    double inv = 1.0 / ssum;
#pragma unroll
    for (int e = 0; e < 64; ++e)
        outp[(size_t)row * E + e] =
            ((selm >> e) & 1ull) ? (float)(exp(lg[e] - vals[0]) * inv) : 0.0f;
#pragma unroll
    for (int i = 0; i < TOPK; ++i)
        outi[(size_t)row * TOPK + i] = (float)idx[i];
}

// ---------------------------------------------------------------------------
extern "C" void kernel_launch(void* const* d_in, const int* in_sizes, int n_in,
                              void* d_out, int out_size, void* d_ws, size_t ws_size,
                              hipStream_t stream) {
    (void)in_sizes; (void)n_in; (void)out_size;
    const float* x = (const float*)d_in[0];
    const float* W = (const float*)d_in[1];
    const float* b = (const float*)d_in[2];

    float* outp = (float*)d_out;
    float* outi = outp + (size_t)M * E;

    const size_t wh_off   = 0;
    const size_t wl_off   = wh_off + sizeof(short) * (size_t)E * K;   // +512 KB
    const size_t cnt_off  = wl_off + sizeof(short) * (size_t)E * K;   // +512 KB
    const size_t list_off = cnt_off + 256;
    const size_t part_off = list_off + (size_t)M * sizeof(int);
    const size_t dsum_off = part_off + (size_t)SPLIT * M * E * sizeof(float);
    const size_t need     = dsum_off + (size_t)RCAP * FKS * E * sizeof(double);

    if (ws_size >= need) {
        short*  Whf  = (short*)((char*)d_ws + wh_off);
        short*  Wlf  = (short*)((char*)d_ws + wl_off);
        int*    cnt  = (int*)((char*)d_ws + cnt_off);
        int*    list = (int*)((char*)d_ws + list_off);
        float*  part = (float*)((char*)d_ws + part_off);
        double* dsum = (double*)((char*)d_ws + dsum_off);

        prep_kernel<<<(E * K) / 256, 256, 0, stream>>>(W, Whf, Wlf, cnt);
        gate_kernel<<<(M / 64) * SPLIT, 256, 0, stream>>>(x, Whf, Wlf, part);
        reduce_kernel<<<M / 4, 256, 0, stream>>>(part, b, outp, outi, cnt, list);
        fix1_kernel<<<4096, 256, 0, stream>>>(x, W, dsum, cnt, list);
        fix2_kernel<<<1024, 64, 0, stream>>>(dsum, b, outp, outi, cnt, list);
    } else {
        fallback_kernel<<<M / 64, 64, 0, stream>>>(x, W, b, outp, outi);
    }
}